// Round 3
// baseline (3468.737 us; speedup 1.0000x reference)
//
#include <hip/hip_runtime.h>
#include <hip/hip_fp16.h>
#include <stdint.h>

// MDRNN: 2-level bidirectional LSTM, S=2048 steps, B=64, H=128, I=256, O=88.
// Scan kernel v2: split-K (4 lanes/unit) + DPP quad butterfly reduction,
// one raw s_barrier per step, G stored transposed for 8-step uint4 prefetch.

typedef _Float16 f16;
typedef _Float16 f16x2 __attribute__((ext_vector_type(2)));
typedef _Float16 f16x4 __attribute__((ext_vector_type(4)));
typedef _Float16 f16x8 __attribute__((ext_vector_type(8)));
typedef float f32x4 __attribute__((ext_vector_type(4)));

#if defined(__has_builtin)
#if __has_builtin(__builtin_amdgcn_fdot2)
#define HAVE_FDOT2 1
#endif
#endif

static __device__ __forceinline__ float fdot2a(uint32_t a, uint32_t b, float c) {
#ifdef HAVE_FDOT2
    return __builtin_amdgcn_fdot2(__builtin_bit_cast(f16x2, a),
                                  __builtin_bit_cast(f16x2, b), c, false);
#else
    f16x2 av = __builtin_bit_cast(f16x2, a), bv = __builtin_bit_cast(f16x2, b);
    return c + (float)av.x * (float)bv.x + (float)av.y * (float)bv.y;
#endif
}

template <int CTRL>
static __device__ __forceinline__ float qperm(float v) {
    int r = __builtin_amdgcn_update_dpp(0, __builtin_bit_cast(int, v), CTRL, 0xf, 0xf, true);
    return __builtin_bit_cast(float, r);
}

static __device__ __forceinline__ float fsig(float x)  { return 1.f / (1.f + __expf(-x)); }
static __device__ __forceinline__ float ftanh(float x) { return 1.f - 2.f / (__expf(2.f * x) + 1.f); }

// ---------------- conversions ----------------

__global__ __launch_bounds__(256) void k_convert_x(const float* __restrict__ x,
                                                   f16* __restrict__ xh) {
    // pure convert: [64][2048][256] fp32 -> same layout fp16 (M = b*2048+s)
    size_t id = (size_t)blockIdx.x * 256 + threadIdx.x;  // 4,194,304 threads x 8 elems
    const float4* src = (const float4*)(x + id * 8);
    float4 v0 = src[0], v1 = src[1];
    f16x8 o = {(f16)v0.x, (f16)v0.y, (f16)v0.z, (f16)v0.w,
               (f16)v1.x, (f16)v1.y, (f16)v1.z, (f16)v1.w};
    *(f16x8*)(xh + id * 8) = o;
}

__global__ __launch_bounds__(256) void k_convert_w(const float* __restrict__ src,
                                                   f16* __restrict__ dst, int n8) {
    int id = blockIdx.x * 256 + threadIdx.x;
    if (id >= n8) return;
    const float4* sp = (const float4*)(src + (size_t)id * 8);
    float4 v0 = sp[0], v1 = sp[1];
    f16x8 o = {(f16)v0.x, (f16)v0.y, (f16)v0.z, (f16)v0.w,
               (f16)v1.x, (f16)v1.y, (f16)v1.z, (f16)v1.w};
    *(f16x8*)(dst + (size_t)id * 8) = o;
}

// ---------------- MFMA GEMM: C^T[N][M] = (A[M][K] * B[N][K]^T)^T  fp16 ----------------

#define BM 128
#define BN 128
#define BKK 32
#define LDT 40   // padded LDS row stride (fp16 elems)

__global__ __launch_bounds__(256) void k_gemm(const f16* __restrict__ A,
                                              const f16* __restrict__ B,
                                              f16* __restrict__ C,   // transposed [N][M]
                                              int M, int N, int K) {
    __shared__ __align__(16) f16 As[BM * LDT];
    __shared__ __align__(16) f16 Bs[BN * LDT];
    const int tid  = threadIdx.x;
    const int m0   = blockIdx.x * BM;
    const int n0   = blockIdx.y * BN;
    const int lane = tid & 63;
    const int wave = tid >> 6;
    const int wm   = (wave & 1) * 64;
    const int wn   = (wave >> 1) * 64;
    const int r    = tid >> 1;
    const int koff = (tid & 1) * 16;
    const int mrow = lane & 15;
    const int kof  = (lane >> 4) * 8;

    f32x4 acc[4][4];
#pragma unroll
    for (int i = 0; i < 4; ++i)
#pragma unroll
        for (int j = 0; j < 4; ++j) acc[i][j] = (f32x4){0.f, 0.f, 0.f, 0.f};

    for (int k0 = 0; k0 < K; k0 += BKK) {
        uint4 a0 = *(const uint4*)(A + (size_t)(m0 + r) * K + k0 + koff);
        uint4 a1 = *(const uint4*)(A + (size_t)(m0 + r) * K + k0 + koff + 8);
        uint4 b0 = *(const uint4*)(B + (size_t)(n0 + r) * K + k0 + koff);
        uint4 b1 = *(const uint4*)(B + (size_t)(n0 + r) * K + k0 + koff + 8);
        *(uint4*)(As + r * LDT + koff)     = a0;
        *(uint4*)(As + r * LDT + koff + 8) = a1;
        *(uint4*)(Bs + r * LDT + koff)     = b0;
        *(uint4*)(Bs + r * LDT + koff + 8) = b1;
        __syncthreads();
        f16x8 af[4], bfr[4];
#pragma unroll
        for (int i = 0; i < 4; ++i)
            af[i] = *(const f16x8*)(As + (wm + i * 16 + mrow) * LDT + kof);
#pragma unroll
        for (int j = 0; j < 4; ++j)
            bfr[j] = *(const f16x8*)(Bs + (wn + j * 16 + mrow) * LDT + kof);
#pragma unroll
        for (int i = 0; i < 4; ++i)
#pragma unroll
            for (int j = 0; j < 4; ++j)
                acc[i][j] = __builtin_amdgcn_mfma_f32_16x16x32_f16(af[i], bfr[j], acc[i][j], 0, 0, 0);
        __syncthreads();
    }
    // C/D layout: col = lane&15 (N side), row = (lane>>4)*4 + reg (M side).
    // Store transposed: C^T[n][m], regs rr are contiguous in m -> one 8B store.
    const int crow = (lane >> 4) * 4;
#pragma unroll
    for (int i = 0; i < 4; ++i) {
#pragma unroll
        for (int j = 0; j < 4; ++j) {
            int cn   = n0 + wn + j * 16 + (lane & 15);
            int rowm = m0 + wm + i * 16 + crow;
            f16x4 v = {(f16)acc[i][j][0], (f16)acc[i][j][1],
                       (f16)acc[i][j][2], (f16)acc[i][j][3]};
            *(f16x4*)(C + (size_t)cn * M + rowm) = v;
        }
    }
}

// ---------------- recurrent LSTM scan (split-K + DPP) ----------------
// One WG per (batch, direction), 512 threads: t = u*4 + kc
//   u  = t>>2 : hidden unit 0..127
//   kc = t&3  : k-chunk (h elements kc*32 .. kc*32+31)
// Thread computes partials of all 4 gates of unit u over its 32-elem h chunk,
// reduces across the 4 kc lanes with DPP quad_perm butterfly (VALU pipe).
// Weights: 4 gates x 16 dwords = 64 VGPRs/thread, loaded once.
// G preacts transposed [1024][131072]: uint4 = 8 steps per load, 1 block ahead.

__global__ __launch_bounds__(512) void k_lstm(
    const f16* __restrict__ G,              // [1024][131072] transposed preacts
    const f16* __restrict__ Whh,            // [2][512][128] fp16
    const float* __restrict__ bih,          // [2][512]
    const float* __restrict__ bhh,          // [2][512]
    f16* __restrict__ tout,                 // [131072][256] fp16 (flags&1)
    float* __restrict__ hfin,               // [64][256] fp32 (flags&2)
    const int S, const int flags) {
    const int b   = blockIdx.x >> 1;
    const int dir = blockIdx.x & 1;
    const int t   = threadIdx.x;
    const int u   = t >> 2;
    const int kc  = t & 3;

    __shared__ __align__(16) f16 hb[2][128];

    // weights: gate q, chunk kc of row q*128+u
    uint32_t w[4][16];
#pragma unroll
    for (int q = 0; q < 4; ++q) {
        const uint4* wp = (const uint4*)(Whh + ((size_t)(dir * 512 + q * 128 + u) * 128 + kc * 32));
#pragma unroll
        for (int jj = 0; jj < 4; ++jj) {
            uint4 qd = wp[jj];
            w[q][4 * jj + 0] = qd.x; w[q][4 * jj + 1] = qd.y;
            w[q][4 * jj + 2] = qd.z; w[q][4 * jj + 3] = qd.w;
        }
    }
    const int rowg = dir * 512 + kc * 128 + u;    // this thread's G row (gate kc of unit u)
    const float bias = bih[rowg] + bhh[rowg];
    const float mk0 = (kc == 0) ? 1.f : 0.f;
    const float mk1 = (kc == 1) ? 1.f : 0.f;
    const float mk2 = (kc == 2) ? 1.f : 0.f;
    const float mk3 = (kc == 3) ? 1.f : 0.f;

    if (t < 64) ((uint32_t*)hb)[64 + t] = 0u;     // zero hb[1] (h(-1))
    float c = 0.f, h = 0.f;
    __syncthreads();

    const f16* gp = G + (size_t)rowg * 131072 + (size_t)b * 2048;
    f16* toutp = tout + ((size_t)b * 2048) * 256 + dir * 128 + (t & 15) * 8;

    uint4 gblk = *(const uint4*)(gp);             // steps 0..7
    for (int sb = 0; sb < S; sb += 8) {
        const int nofs = (sb + 8 < S) ? (sb + 8) : sb;
        uint4 gnblk = *(const uint4*)(gp + nofs); // prefetch next block (stays in flight)
#pragma unroll
        for (int j = 0; j < 8; ++j) {
            const int s = sb + j;
            f16* hcur = hb[j & 1];
            const f16* hprv = hb[(j & 1) ^ 1];
            // stream previous step's h to tout (contiguous 256B per chain-step)
            if ((flags & 1) && t < 16 && s > 0) {
                uint4 hv16 = *(const uint4*)(hprv + t * 8);
                *(uint4*)(toutp + (size_t)(s - 1) * 256) = hv16;
            }
            float p0 = 0.f, p1 = 0.f, p2 = 0.f, p3 = 0.f;
            const uint4* hv = (const uint4*)(hprv + kc * 32);
#pragma unroll
            for (int jj = 0; jj < 4; ++jj) {
                uint4 hq = hv[jj];
                p0 = fdot2a(w[0][4 * jj + 0], hq.x, p0);
                p1 = fdot2a(w[1][4 * jj + 0], hq.x, p1);
                p2 = fdot2a(w[2][4 * jj + 0], hq.x, p2);
                p3 = fdot2a(w[3][4 * jj + 0], hq.x, p3);
                p0 = fdot2a(w[0][4 * jj + 1], hq.y, p0);
                p1 = fdot2a(w[1][4 * jj + 1], hq.y, p1);
                p2 = fdot2a(w[2][4 * jj + 1], hq.y, p2);
                p3 = fdot2a(w[3][4 * jj + 1], hq.y, p3);
                p0 = fdot2a(w[0][4 * jj + 2], hq.z, p0);
                p1 = fdot2a(w[1][4 * jj + 2], hq.z, p1);
                p2 = fdot2a(w[2][4 * jj + 2], hq.z, p2);
                p3 = fdot2a(w[3][4 * jj + 2], hq.z, p3);
                p0 = fdot2a(w[0][4 * jj + 3], hq.w, p0);
                p1 = fdot2a(w[1][4 * jj + 3], hq.w, p1);
                p2 = fdot2a(w[2][4 * jj + 3], hq.w, p2);
                p3 = fdot2a(w[3][4 * jj + 3], hq.w, p3);
            }
            // inject x-preact + bias into gate kc only (this thread's G row)
            {
                uint32_t d = ((const uint32_t*)&gblk)[j >> 1];
                uint16_t us = (uint16_t)((j & 1) ? (d >> 16) : (d & 0xffff));
                float gxb = (float)__builtin_bit_cast(f16, us) + bias;
                p0 = __builtin_fmaf(mk0, gxb, p0);
                p1 = __builtin_fmaf(mk1, gxb, p1);
                p2 = __builtin_fmaf(mk2, gxb, p2);
                p3 = __builtin_fmaf(mk3, gxb, p3);
            }
            // DPP quad butterfly all-reduce across the 4 kc lanes
            p0 += qperm<0xB1>(p0); p1 += qperm<0xB1>(p1);
            p2 += qperm<0xB1>(p2); p3 += qperm<0xB1>(p3);
            p0 += qperm<0x4E>(p0); p1 += qperm<0x4E>(p1);
            p2 += qperm<0x4E>(p2); p3 += qperm<0x4E>(p3);
            // elementwise cell update (redundant in all 4 lanes, identical values)
            float si = fsig(p0), sf = fsig(p1), so = fsig(p3);
            c = sf * c + si * ftanh(p2);
            h = so * ftanh(c);
            if (kc == 0) hcur[u] = (f16)h;
            // LDS-only drain + barrier: G prefetch stays in flight across it
            __asm__ __volatile__("s_waitcnt lgkmcnt(0)\n\ts_barrier" ::: "memory");
        }
        gblk = gnblk;
    }
    if ((flags & 1) && t < 16) {                  // flush final step's h
        uint4 hv16 = *(const uint4*)(hb[(2048 - 1) & 1] + t * 8);
        *(uint4*)(toutp + (size_t)(S - 1) * 256) = hv16;
    }
    if ((flags & 2) && kc == 0) hfin[b * 256 + dir * 128 + u] = h;
}

// ---------------- output projection ----------------

__global__ __launch_bounds__(128) void k_out(const float* __restrict__ hp,  // [64][256]
                                             const float* __restrict__ Wo,  // [88][256]
                                             const float* __restrict__ bo,  // [88]
                                             float* __restrict__ out) {     // [64][88]
    const int b = blockIdx.x;
    const int t = threadIdx.x;
    __shared__ float hs[256];
    hs[t] = hp[b * 256 + t];
    hs[t + 128] = hp[b * 256 + 128 + t];
    __syncthreads();
    if (t < 88) {
        float acc = bo[t];
        const float* wr = Wo + t * 256;
#pragma unroll 4
        for (int k = 0; k < 256; ++k) acc += wr[k] * hs[k];
        out[b * 88 + t] = acc;
    }
}

// ---------------- launch ----------------

extern "C" void kernel_launch(void* const* d_in, const int* in_sizes, int n_in,
                              void* d_out, int out_size, void* d_ws, size_t ws_size,
                              hipStream_t stream) {
    const float* x    = (const float*)d_in[0];
    const float* Wtih = (const float*)d_in[1];
    const float* Wthh = (const float*)d_in[2];
    const float* btih = (const float*)d_in[3];
    const float* bthh = (const float*)d_in[4];
    const float* Wpih = (const float*)d_in[5];
    const float* Wphh = (const float*)d_in[6];
    const float* bpih = (const float*)d_in[7];
    const float* bphh = (const float*)d_in[8];
    const float* Wo   = (const float*)d_in[9];
    const float* bo   = (const float*)d_in[10];

    char* ws = (char*)d_ws;
    f16*   xh    = (f16*)(ws + 0);            //  67,108,864 B  [131072][256]
    f16*   G     = (f16*)(ws + 67108864);     // 268,435,456 B  [1024][131072] transposed
    f16*   tout  = (f16*)(ws + 335544320);    //  67,108,864 B  [131072][256]
    f16*   wtih  = (f16*)(ws + 402653184);    //     524,288 B
    f16*   wthh  = (f16*)(ws + 403177472);    //     262,144 B
    f16*   wpih  = (f16*)(ws + 403439616);    //     524,288 B
    f16*   wphh  = (f16*)(ws + 403963904);    //     262,144 B
    float* hp    = (float*)(ws + 404226048);  //      65,536 B  (~405 MB total)

    k_convert_x<<<16384, 256, 0, stream>>>(x, xh);
    k_convert_w<<<128, 256, 0, stream>>>(Wtih, wtih, 32768);
    k_convert_w<<<64,  256, 0, stream>>>(Wthh, wthh, 16384);
    k_convert_w<<<128, 256, 0, stream>>>(Wpih, wpih, 32768);
    k_convert_w<<<64,  256, 0, stream>>>(Wphh, wphh, 16384);

    // G^T = (xh @ Wt_ih^T)^T
    k_gemm<<<dim3(1024, 8), 256, 0, stream>>>(xh, wtih, G, 131072, 1024, 256);
    // time-level scan -> tout
    k_lstm<<<128, 512, 0, stream>>>(G, wthh, btih, bthh, tout, nullptr, 2048, 1);
    // G^T = (tout @ Wp_ih^T)^T
    k_gemm<<<dim3(1024, 8), 256, 0, stream>>>(tout, wpih, G, 131072, 1024, 256);
    // pitch-level scan -> final h
    k_lstm<<<128, 512, 0, stream>>>(G, wphh, bpih, bphh, nullptr, hp, 2048, 2);
    // output projection
    k_out<<<64, 128, 0, stream>>>(hp, Wo, bo, (float*)d_out);
}

// Round 4
// 3438.471 us; speedup vs baseline: 1.0088x; 1.0088x over previous
//
#include <hip/hip_runtime.h>
#include <hip/hip_fp16.h>
#include <stdint.h>

// MDRNN: 2-level bidirectional LSTM, S=2048 steps, B=64, H=128, I=256, O=88.
// Scan v3: split-K (4 lanes/unit) + DPP quad butterfly; weights pinned in
// VGPRs via asm-opaque trick (defeats "memory"-clobber rematerialization);
// G stored BLOCK-transposed [S/8][64][1024][8] so scan loads are coalesced
// (one uint4 = 8 steps of one gate-row) and GEMM-epilogue stores stay dense.

typedef _Float16 f16;
typedef _Float16 f16x2 __attribute__((ext_vector_type(2)));
typedef _Float16 f16x4 __attribute__((ext_vector_type(4)));
typedef _Float16 f16x8 __attribute__((ext_vector_type(8)));
typedef float f32x4 __attribute__((ext_vector_type(4)));

#if defined(__has_builtin)
#if __has_builtin(__builtin_amdgcn_fdot2)
#define HAVE_FDOT2 1
#endif
#endif

static __device__ __forceinline__ float fdot2a(uint32_t a, uint32_t b, float c) {
#ifdef HAVE_FDOT2
    return __builtin_amdgcn_fdot2(__builtin_bit_cast(f16x2, a),
                                  __builtin_bit_cast(f16x2, b), c, false);
#else
    f16x2 av = __builtin_bit_cast(f16x2, a), bv = __builtin_bit_cast(f16x2, b);
    return c + (float)av.x * (float)bv.x + (float)av.y * (float)bv.y;
#endif
}

template <int CTRL>
static __device__ __forceinline__ float qperm(float v) {
    int r = __builtin_amdgcn_update_dpp(0, __builtin_bit_cast(int, v), CTRL, 0xf, 0xf, true);
    return __builtin_bit_cast(float, r);
}

static __device__ __forceinline__ float fsig(float x)  { return 1.f / (1.f + __expf(-x)); }
static __device__ __forceinline__ float ftanh(float x) { return 1.f - 2.f / (__expf(2.f * x) + 1.f); }

// ---------------- conversions ----------------

__global__ __launch_bounds__(256) void k_convert_x(const float* __restrict__ x,
                                                   f16* __restrict__ xh) {
    // pure convert: [64][2048][256] fp32 -> same layout fp16 (M = b*2048+s)
    size_t id = (size_t)blockIdx.x * 256 + threadIdx.x;  // 4,194,304 threads x 8 elems
    const float4* src = (const float4*)(x + id * 8);
    float4 v0 = src[0], v1 = src[1];
    f16x8 o = {(f16)v0.x, (f16)v0.y, (f16)v0.z, (f16)v0.w,
               (f16)v1.x, (f16)v1.y, (f16)v1.z, (f16)v1.w};
    *(f16x8*)(xh + id * 8) = o;
}

__global__ __launch_bounds__(256) void k_convert_w(const float* __restrict__ src,
                                                   f16* __restrict__ dst, int n8) {
    int id = blockIdx.x * 256 + threadIdx.x;
    if (id >= n8) return;
    const float4* sp = (const float4*)(src + (size_t)id * 8);
    float4 v0 = sp[0], v1 = sp[1];
    f16x8 o = {(f16)v0.x, (f16)v0.y, (f16)v0.z, (f16)v0.w,
               (f16)v1.x, (f16)v1.y, (f16)v1.z, (f16)v1.w};
    *(f16x8*)(dst + (size_t)id * 8) = o;
}

// ---------------- MFMA GEMM into block-transposed G ----------------
// C layout: [s/8][b][n][s%8]  (M = b*2048+s, n = 0..1023)

#define BM 128
#define BN 128
#define BKK 32
#define LDT 40   // padded LDS row stride (fp16 elems)

__global__ __launch_bounds__(256) void k_gemm(const f16* __restrict__ A,
                                              const f16* __restrict__ B,
                                              f16* __restrict__ C,
                                              int M, int N, int K) {
    __shared__ __align__(16) f16 As[BM * LDT];
    __shared__ __align__(16) f16 Bs[BN * LDT];
    const int tid  = threadIdx.x;
    const int m0   = blockIdx.x * BM;
    const int n0   = blockIdx.y * BN;
    const int lane = tid & 63;
    const int wave = tid >> 6;
    const int wm   = (wave & 1) * 64;
    const int wn   = (wave >> 1) * 64;
    const int r    = tid >> 1;
    const int koff = (tid & 1) * 16;
    const int mrow = lane & 15;
    const int kof  = (lane >> 4) * 8;

    f32x4 acc[4][4];
#pragma unroll
    for (int i = 0; i < 4; ++i)
#pragma unroll
        for (int j = 0; j < 4; ++j) acc[i][j] = (f32x4){0.f, 0.f, 0.f, 0.f};

    for (int k0 = 0; k0 < K; k0 += BKK) {
        uint4 a0 = *(const uint4*)(A + (size_t)(m0 + r) * K + k0 + koff);
        uint4 a1 = *(const uint4*)(A + (size_t)(m0 + r) * K + k0 + koff + 8);
        uint4 b0 = *(const uint4*)(B + (size_t)(n0 + r) * K + k0 + koff);
        uint4 b1 = *(const uint4*)(B + (size_t)(n0 + r) * K + k0 + koff + 8);
        *(uint4*)(As + r * LDT + koff)     = a0;
        *(uint4*)(As + r * LDT + koff + 8) = a1;
        *(uint4*)(Bs + r * LDT + koff)     = b0;
        *(uint4*)(Bs + r * LDT + koff + 8) = b1;
        __syncthreads();
        f16x8 af[4], bfr[4];
#pragma unroll
        for (int i = 0; i < 4; ++i)
            af[i] = *(const f16x8*)(As + (wm + i * 16 + mrow) * LDT + kof);
#pragma unroll
        for (int j = 0; j < 4; ++j)
            bfr[j] = *(const f16x8*)(Bs + (wn + j * 16 + mrow) * LDT + kof);
#pragma unroll
        for (int i = 0; i < 4; ++i)
#pragma unroll
            for (int j = 0; j < 4; ++j)
                acc[i][j] = __builtin_amdgcn_mfma_f32_16x16x32_f16(af[i], bfr[j], acc[i][j], 0, 0, 0);
        __syncthreads();
    }
    // C/D layout: col = lane&15 (N side), row = (lane>>4)*4 + reg (M side).
    // Store to blocked layout: [(s>>3)][b][n][(s&7)], 4 regs contiguous in s&7.
    const int crow = (lane >> 4) * 4;
#pragma unroll
    for (int i = 0; i < 4; ++i) {
#pragma unroll
        for (int j = 0; j < 4; ++j) {
            int cn = n0 + wn + j * 16 + (lane & 15);
            int m  = m0 + wm + i * 16 + crow;
            int bb = m >> 11;          // batch
            int s  = m & 2047;         // step
            f16x4 v = {(f16)acc[i][j][0], (f16)acc[i][j][1],
                       (f16)acc[i][j][2], (f16)acc[i][j][3]};
            size_t addr = ((((size_t)(s >> 3) * 64 + bb) * 1024) + cn) * 8 + (s & 7);
            *(f16x4*)(C + addr) = v;
        }
    }
}

// ---------------- recurrent LSTM scan (split-K + DPP, pinned weights) ----------------
// One WG per (batch, direction), 512 threads: t = u*4 + kc
//   u  = t>>2 : hidden unit 0..127
//   kc = t&3  : k-chunk (h elements kc*32 .. kc*32+31)
// Weights: 4 gates x 16 dwords = 64 VGPRs/thread, loaded once, made asm-opaque
// so the per-step "memory"-clobber barrier cannot force reloads from L2.
// G blocked [S/8][64][1024][8]: one uint4 = 8 steps of this thread's gate-row.

__global__ __launch_bounds__(512, 2) void k_lstm(
    const f16* __restrict__ G,              // [S/8][64][1024][8]
    const f16* __restrict__ Whh,            // [2][512][128] fp16
    const float* __restrict__ bih,          // [2][512]
    const float* __restrict__ bhh,          // [2][512]
    f16* __restrict__ tout,                 // [131072][256] fp16 (flags&1)
    float* __restrict__ hfin,               // [64][256] fp32 (flags&2)
    const int S, const int flags) {
    const int b   = blockIdx.x >> 1;
    const int dir = blockIdx.x & 1;
    const int t   = threadIdx.x;
    const int u   = t >> 2;
    const int kc  = t & 3;

    __shared__ __align__(16) f16 hb[2][128];

    // weights: gate q, chunk kc of row q*128+u
    uint32_t w[4][16];
#pragma unroll
    for (int q = 0; q < 4; ++q) {
        const uint4* wp = (const uint4*)(Whh + ((size_t)(dir * 512 + q * 128 + u) * 128 + kc * 32));
#pragma unroll
        for (int jj = 0; jj < 4; ++jj) {
            uint4 qd = wp[jj];
            w[q][4 * jj + 0] = qd.x; w[q][4 * jj + 1] = qd.y;
            w[q][4 * jj + 2] = qd.z; w[q][4 * jj + 3] = qd.w;
        }
    }
    const int rowg = dir * 512 + kc * 128 + u;    // this thread's G row (gate kc of unit u)
    float bias = bih[rowg] + bhh[rowg];
    // pin weights + bias in VGPRs: opaque to the optimizer, cannot be
    // rematerialized from memory after the barrier's "memory" clobber
#pragma unroll
    for (int q = 0; q < 4; ++q)
#pragma unroll
        for (int i = 0; i < 16; ++i) __asm__("" : "+v"(w[q][i]));
    __asm__("" : "+v"(bias));

    const float mk0 = (kc == 0) ? 1.f : 0.f;
    const float mk1 = (kc == 1) ? 1.f : 0.f;
    const float mk2 = (kc == 2) ? 1.f : 0.f;
    const float mk3 = (kc == 3) ? 1.f : 0.f;

    if (t < 64) ((uint32_t*)hb)[64 + t] = 0u;     // zero hb[1] (h(-1))
    float c = 0.f, h = 0.f;
    __syncthreads();

    // blocked G: base for blk 0
    const f16* gp = G + ((size_t)b * 1024 + rowg) * 8;
    f16* toutp = tout + ((size_t)b * 2048) * 256 + dir * 128 + (t & 15) * 8;

    uint4 gblk = *(const uint4*)(gp);             // steps 0..7
    for (int sb = 0; sb < S; sb += 8) {
        const size_t nblk = (size_t)((sb + 8 < S) ? (sb >> 3) + 1 : (sb >> 3));
        uint4 gnblk = *(const uint4*)(gp + nblk * 524288);  // prefetch next block
#pragma unroll
        for (int j = 0; j < 8; ++j) {
            const int s = sb + j;
            f16* hcur = hb[j & 1];
            const f16* hprv = hb[(j & 1) ^ 1];
            // stream previous step's h to tout (contiguous 256B per chain-step)
            if ((flags & 1) && t < 16 && s > 0) {
                uint4 hv16 = *(const uint4*)(hprv + t * 8);
                *(uint4*)(toutp + (size_t)(s - 1) * 256) = hv16;
            }
            float p0 = 0.f, p1 = 0.f, p2 = 0.f, p3 = 0.f;
            const uint4* hv = (const uint4*)(hprv + kc * 32);
#pragma unroll
            for (int jj = 0; jj < 4; ++jj) {
                uint4 hq = hv[jj];
                p0 = fdot2a(w[0][4 * jj + 0], hq.x, p0);
                p1 = fdot2a(w[1][4 * jj + 0], hq.x, p1);
                p2 = fdot2a(w[2][4 * jj + 0], hq.x, p2);
                p3 = fdot2a(w[3][4 * jj + 0], hq.x, p3);
                p0 = fdot2a(w[0][4 * jj + 1], hq.y, p0);
                p1 = fdot2a(w[1][4 * jj + 1], hq.y, p1);
                p2 = fdot2a(w[2][4 * jj + 1], hq.y, p2);
                p3 = fdot2a(w[3][4 * jj + 1], hq.y, p3);
                p0 = fdot2a(w[0][4 * jj + 2], hq.z, p0);
                p1 = fdot2a(w[1][4 * jj + 2], hq.z, p1);
                p2 = fdot2a(w[2][4 * jj + 2], hq.z, p2);
                p3 = fdot2a(w[3][4 * jj + 2], hq.z, p3);
                p0 = fdot2a(w[0][4 * jj + 3], hq.w, p0);
                p1 = fdot2a(w[1][4 * jj + 3], hq.w, p1);
                p2 = fdot2a(w[2][4 * jj + 3], hq.w, p2);
                p3 = fdot2a(w[3][4 * jj + 3], hq.w, p3);
            }
            // inject x-preact + bias into gate kc only (this thread's G row)
            {
                uint32_t d = ((const uint32_t*)&gblk)[j >> 1];
                uint16_t us = (uint16_t)((j & 1) ? (d >> 16) : (d & 0xffff));
                float gxb = (float)__builtin_bit_cast(f16, us) + bias;
                p0 = __builtin_fmaf(mk0, gxb, p0);
                p1 = __builtin_fmaf(mk1, gxb, p1);
                p2 = __builtin_fmaf(mk2, gxb, p2);
                p3 = __builtin_fmaf(mk3, gxb, p3);
            }
            // DPP quad butterfly all-reduce across the 4 kc lanes
            p0 += qperm<0xB1>(p0); p1 += qperm<0xB1>(p1);
            p2 += qperm<0xB1>(p2); p3 += qperm<0xB1>(p3);
            p0 += qperm<0x4E>(p0); p1 += qperm<0x4E>(p1);
            p2 += qperm<0x4E>(p2); p3 += qperm<0x4E>(p3);
            // elementwise cell update (identical in all 4 kc lanes)
            float si = fsig(p0), sf = fsig(p1), so = fsig(p3);
            c = sf * c + si * ftanh(p2);
            h = so * ftanh(c);
            if (kc == 0) hcur[u] = (f16)h;
            // LDS-only drain + barrier: G prefetch stays in flight across it
            __asm__ __volatile__("s_waitcnt lgkmcnt(0)\n\ts_barrier" ::: "memory");
        }
        gblk = gnblk;
    }
    if ((flags & 1) && t < 16) {                  // flush final step's h
        uint4 hv16 = *(const uint4*)(hb[(2048 - 1) & 1] + t * 8);
        *(uint4*)(toutp + (size_t)(S - 1) * 256) = hv16;
    }
    if ((flags & 2) && kc == 0) hfin[b * 256 + dir * 128 + u] = h;
}

// ---------------- output projection ----------------

__global__ __launch_bounds__(128) void k_out(const float* __restrict__ hp,  // [64][256]
                                             const float* __restrict__ Wo,  // [88][256]
                                             const float* __restrict__ bo,  // [88]
                                             float* __restrict__ out) {     // [64][88]
    const int b = blockIdx.x;
    const int t = threadIdx.x;
    __shared__ float hs[256];
    hs[t] = hp[b * 256 + t];
    hs[t + 128] = hp[b * 256 + 128 + t];
    __syncthreads();
    if (t < 88) {
        float acc = bo[t];
        const float* wr = Wo + t * 256;
#pragma unroll 4
        for (int k = 0; k < 256; ++k) acc += wr[k] * hs[k];
        out[b * 88 + t] = acc;
    }
}

// ---------------- launch ----------------

extern "C" void kernel_launch(void* const* d_in, const int* in_sizes, int n_in,
                              void* d_out, int out_size, void* d_ws, size_t ws_size,
                              hipStream_t stream) {
    const float* x    = (const float*)d_in[0];
    const float* Wtih = (const float*)d_in[1];
    const float* Wthh = (const float*)d_in[2];
    const float* btih = (const float*)d_in[3];
    const float* bthh = (const float*)d_in[4];
    const float* Wpih = (const float*)d_in[5];
    const float* Wphh = (const float*)d_in[6];
    const float* bpih = (const float*)d_in[7];
    const float* bphh = (const float*)d_in[8];
    const float* Wo   = (const float*)d_in[9];
    const float* bo   = (const float*)d_in[10];

    char* ws = (char*)d_ws;
    f16*   xh    = (f16*)(ws + 0);            //  67,108,864 B  [131072][256]
    f16*   G     = (f16*)(ws + 67108864);     // 268,435,456 B  [256][64][1024][8]
    f16*   tout  = (f16*)(ws + 335544320);    //  67,108,864 B  [131072][256]
    f16*   wtih  = (f16*)(ws + 402653184);    //     524,288 B
    f16*   wthh  = (f16*)(ws + 403177472);    //     262,144 B
    f16*   wpih  = (f16*)(ws + 403439616);    //     524,288 B
    f16*   wphh  = (f16*)(ws + 403963904);    //     262,144 B
    float* hp    = (float*)(ws + 404226048);  //      65,536 B  (~405 MB total)

    k_convert_x<<<16384, 256, 0, stream>>>(x, xh);
    k_convert_w<<<128, 256, 0, stream>>>(Wtih, wtih, 32768);
    k_convert_w<<<64,  256, 0, stream>>>(Wthh, wthh, 16384);
    k_convert_w<<<128, 256, 0, stream>>>(Wpih, wpih, 32768);
    k_convert_w<<<64,  256, 0, stream>>>(Wphh, wphh, 16384);

    // G = blocked (xh @ Wt_ih^T)
    k_gemm<<<dim3(1024, 8), 256, 0, stream>>>(xh, wtih, G, 131072, 1024, 256);
    // time-level scan -> tout
    k_lstm<<<128, 512, 0, stream>>>(G, wthh, btih, bthh, tout, nullptr, 2048, 1);
    // G = blocked (tout @ Wp_ih^T)
    k_gemm<<<dim3(1024, 8), 256, 0, stream>>>(tout, wpih, G, 131072, 1024, 256);
    // pitch-level scan -> final h
    k_lstm<<<128, 512, 0, stream>>>(G, wphh, bpih, bphh, nullptr, hp, 2048, 2);
    // output projection
    k_out<<<64, 128, 0, stream>>>(hp, Wo, bo, (float*)d_out);
}

// Round 5
// 3430.029 us; speedup vs baseline: 1.0113x; 1.0025x over previous
//
#include <hip/hip_runtime.h>
#include <hip/hip_fp16.h>
#include <stdint.h>

// MDRNN: 2-level bidirectional LSTM, S=2048 steps, B=64, H=128, I=256, O=88.
// Scan v4: split-K (4 lanes/unit) + DPP quad butterfly; weights pinned in
// VGPRs. KEY FIX vs v3: amdgpu_waves_per_eu(2,2) pins the register-allocator
// occupancy target at 2 waves/EU (256-VGPR budget) — v3's allocator targeted
// 8 waves/SIMD (64 VGPRs) and silently spilled the 64-dword weight array to
// scratch, re-streaming 128 KB/step/CU from L2 (the real 1815-cyc/step bound).

typedef _Float16 f16;
typedef _Float16 f16x2 __attribute__((ext_vector_type(2)));
typedef _Float16 f16x4 __attribute__((ext_vector_type(4)));
typedef _Float16 f16x8 __attribute__((ext_vector_type(8)));
typedef float f32x4 __attribute__((ext_vector_type(4)));

#if defined(__has_builtin)
#if __has_builtin(__builtin_amdgcn_fdot2)
#define HAVE_FDOT2 1
#endif
#endif

static __device__ __forceinline__ float fdot2a(uint32_t a, uint32_t b, float c) {
#ifdef HAVE_FDOT2
    return __builtin_amdgcn_fdot2(__builtin_bit_cast(f16x2, a),
                                  __builtin_bit_cast(f16x2, b), c, false);
#else
    f16x2 av = __builtin_bit_cast(f16x2, a), bv = __builtin_bit_cast(f16x2, b);
    return c + (float)av.x * (float)bv.x + (float)av.y * (float)bv.y;
#endif
}

template <int CTRL>
static __device__ __forceinline__ float qperm(float v) {
    int r = __builtin_amdgcn_update_dpp(0, __builtin_bit_cast(int, v), CTRL, 0xf, 0xf, true);
    return __builtin_bit_cast(float, r);
}

static __device__ __forceinline__ float fsig(float x)  { return 1.f / (1.f + __expf(-x)); }
static __device__ __forceinline__ float ftanh(float x) { return 1.f - 2.f / (__expf(2.f * x) + 1.f); }

// ---------------- conversions ----------------

__global__ __launch_bounds__(256) void k_convert_x(const float* __restrict__ x,
                                                   f16* __restrict__ xh) {
    // pure convert: [64][2048][256] fp32 -> same layout fp16 (M = b*2048+s)
    size_t id = (size_t)blockIdx.x * 256 + threadIdx.x;  // 4,194,304 threads x 8 elems
    const float4* src = (const float4*)(x + id * 8);
    float4 v0 = src[0], v1 = src[1];
    f16x8 o = {(f16)v0.x, (f16)v0.y, (f16)v0.z, (f16)v0.w,
               (f16)v1.x, (f16)v1.y, (f16)v1.z, (f16)v1.w};
    *(f16x8*)(xh + id * 8) = o;
}

__global__ __launch_bounds__(256) void k_convert_w(const float* __restrict__ src,
                                                   f16* __restrict__ dst, int n8) {
    int id = blockIdx.x * 256 + threadIdx.x;
    if (id >= n8) return;
    const float4* sp = (const float4*)(src + (size_t)id * 8);
    float4 v0 = sp[0], v1 = sp[1];
    f16x8 o = {(f16)v0.x, (f16)v0.y, (f16)v0.z, (f16)v0.w,
               (f16)v1.x, (f16)v1.y, (f16)v1.z, (f16)v1.w};
    *(f16x8*)(dst + (size_t)id * 8) = o;
}

// ---------------- MFMA GEMM into block-transposed G ----------------
// C layout: [s/8][b][n][s%8]  (M = b*2048+s, n = 0..1023)

#define BM 128
#define BN 128
#define BKK 32
#define LDT 40   // padded LDS row stride (fp16 elems)

__global__ __launch_bounds__(256) void k_gemm(const f16* __restrict__ A,
                                              const f16* __restrict__ B,
                                              f16* __restrict__ C,
                                              int M, int N, int K) {
    __shared__ __align__(16) f16 As[BM * LDT];
    __shared__ __align__(16) f16 Bs[BN * LDT];
    const int tid  = threadIdx.x;
    const int m0   = blockIdx.x * BM;
    const int n0   = blockIdx.y * BN;
    const int lane = tid & 63;
    const int wave = tid >> 6;
    const int wm   = (wave & 1) * 64;
    const int wn   = (wave >> 1) * 64;
    const int r    = tid >> 1;
    const int koff = (tid & 1) * 16;
    const int mrow = lane & 15;
    const int kof  = (lane >> 4) * 8;

    f32x4 acc[4][4];
#pragma unroll
    for (int i = 0; i < 4; ++i)
#pragma unroll
        for (int j = 0; j < 4; ++j) acc[i][j] = (f32x4){0.f, 0.f, 0.f, 0.f};

    for (int k0 = 0; k0 < K; k0 += BKK) {
        uint4 a0 = *(const uint4*)(A + (size_t)(m0 + r) * K + k0 + koff);
        uint4 a1 = *(const uint4*)(A + (size_t)(m0 + r) * K + k0 + koff + 8);
        uint4 b0 = *(const uint4*)(B + (size_t)(n0 + r) * K + k0 + koff);
        uint4 b1 = *(const uint4*)(B + (size_t)(n0 + r) * K + k0 + koff + 8);
        *(uint4*)(As + r * LDT + koff)     = a0;
        *(uint4*)(As + r * LDT + koff + 8) = a1;
        *(uint4*)(Bs + r * LDT + koff)     = b0;
        *(uint4*)(Bs + r * LDT + koff + 8) = b1;
        __syncthreads();
        f16x8 af[4], bfr[4];
#pragma unroll
        for (int i = 0; i < 4; ++i)
            af[i] = *(const f16x8*)(As + (wm + i * 16 + mrow) * LDT + kof);
#pragma unroll
        for (int j = 0; j < 4; ++j)
            bfr[j] = *(const f16x8*)(Bs + (wn + j * 16 + mrow) * LDT + kof);
#pragma unroll
        for (int i = 0; i < 4; ++i)
#pragma unroll
            for (int j = 0; j < 4; ++j)
                acc[i][j] = __builtin_amdgcn_mfma_f32_16x16x32_f16(af[i], bfr[j], acc[i][j], 0, 0, 0);
        __syncthreads();
    }
    // C/D layout: col = lane&15 (N side), row = (lane>>4)*4 + reg (M side).
    // Store to blocked layout: [(s>>3)][b][n][(s&7)], 4 regs contiguous in s&7.
    const int crow = (lane >> 4) * 4;
#pragma unroll
    for (int i = 0; i < 4; ++i) {
#pragma unroll
        for (int j = 0; j < 4; ++j) {
            int cn = n0 + wn + j * 16 + (lane & 15);
            int m  = m0 + wm + i * 16 + crow;
            int bb = m >> 11;          // batch
            int s  = m & 2047;         // step
            f16x4 v = {(f16)acc[i][j][0], (f16)acc[i][j][1],
                       (f16)acc[i][j][2], (f16)acc[i][j][3]};
            size_t addr = ((((size_t)(s >> 3) * 64 + bb) * 1024) + cn) * 8 + (s & 7);
            *(f16x4*)(C + addr) = v;
        }
    }
}

// ---------------- recurrent LSTM scan (split-K + DPP, pinned weights) ----------------
// One WG per (batch, direction), 512 threads: t = u*4 + kc
//   u  = t>>2 : hidden unit 0..127
//   kc = t&3  : k-chunk (h elements kc*32 .. kc*32+31)
// Weights: 4 gates x 16 dwords = 64 VGPRs/thread, loaded once, asm-opaque.
// amdgpu_waves_per_eu(2,2): exactly 1 WG/CU -> 256-VGPR budget, no spill.
// G blocked [S/8][64][1024][8]: one uint4 = 8 steps of this thread's gate-row.

__global__ void __attribute__((amdgpu_flat_work_group_size(512, 512),
                               amdgpu_waves_per_eu(2, 2))) k_lstm(
    const f16* __restrict__ G,              // [S/8][64][1024][8]
    const f16* __restrict__ Whh,            // [2][512][128] fp16
    const float* __restrict__ bih,          // [2][512]
    const float* __restrict__ bhh,          // [2][512]
    f16* __restrict__ tout,                 // [131072][256] fp16 (flags&1)
    float* __restrict__ hfin,               // [64][256] fp32 (flags&2)
    const int S, const int flags) {
    const int b   = blockIdx.x >> 1;
    const int dir = blockIdx.x & 1;
    const int t   = threadIdx.x;
    const int u   = t >> 2;
    const int kc  = t & 3;

    __shared__ __align__(16) f16 hb[2][128];

    // weights: gate q, chunk kc of row q*128+u
    uint32_t w[4][16];
#pragma unroll
    for (int q = 0; q < 4; ++q) {
        const uint4* wp = (const uint4*)(Whh + ((size_t)(dir * 512 + q * 128 + u) * 128 + kc * 32));
#pragma unroll
        for (int jj = 0; jj < 4; ++jj) {
            uint4 qd = wp[jj];
            w[q][4 * jj + 0] = qd.x; w[q][4 * jj + 1] = qd.y;
            w[q][4 * jj + 2] = qd.z; w[q][4 * jj + 3] = qd.w;
        }
    }
    const int rowg = dir * 512 + kc * 128 + u;    // this thread's G row (gate kc of unit u)
    float bias = bih[rowg] + bhh[rowg];
    // pin weights + bias in VGPRs: opaque to the optimizer, cannot be
    // rematerialized from memory after the barrier's "memory" clobber
#pragma unroll
    for (int q = 0; q < 4; ++q)
#pragma unroll
        for (int i = 0; i < 16; ++i) __asm__("" : "+v"(w[q][i]));
    __asm__("" : "+v"(bias));

    const float mk0 = (kc == 0) ? 1.f : 0.f;
    const float mk1 = (kc == 1) ? 1.f : 0.f;
    const float mk2 = (kc == 2) ? 1.f : 0.f;
    const float mk3 = (kc == 3) ? 1.f : 0.f;

    if (t < 64) ((uint32_t*)hb)[64 + t] = 0u;     // zero hb[1] (h(-1))
    float c = 0.f, h = 0.f;
    __syncthreads();

    // blocked G: base for blk 0
    const f16* gp = G + ((size_t)b * 1024 + rowg) * 8;
    f16* toutp = tout + ((size_t)b * 2048) * 256 + dir * 128 + (t & 15) * 8;

    uint4 gblk = *(const uint4*)(gp);             // steps 0..7
    for (int sb = 0; sb < S; sb += 8) {
        const size_t nblk = (size_t)((sb + 8 < S) ? (sb >> 3) + 1 : (sb >> 3));
        uint4 gnblk = *(const uint4*)(gp + nblk * 524288);  // prefetch next block
#pragma unroll
        for (int j = 0; j < 8; ++j) {
            const int s = sb + j;
            f16* hcur = hb[j & 1];
            const f16* hprv = hb[(j & 1) ^ 1];
            // stream previous step's h to tout (contiguous 256B per chain-step)
            if ((flags & 1) && t < 16 && s > 0) {
                uint4 hv16 = *(const uint4*)(hprv + t * 8);
                *(uint4*)(toutp + (size_t)(s - 1) * 256) = hv16;
            }
            float p0 = 0.f, p1 = 0.f, p2 = 0.f, p3 = 0.f;
            const uint4* hv = (const uint4*)(hprv + kc * 32);
#pragma unroll
            for (int jj = 0; jj < 4; ++jj) {
                uint4 hq = hv[jj];
                p0 = fdot2a(w[0][4 * jj + 0], hq.x, p0);
                p1 = fdot2a(w[1][4 * jj + 0], hq.x, p1);
                p2 = fdot2a(w[2][4 * jj + 0], hq.x, p2);
                p3 = fdot2a(w[3][4 * jj + 0], hq.x, p3);
                p0 = fdot2a(w[0][4 * jj + 1], hq.y, p0);
                p1 = fdot2a(w[1][4 * jj + 1], hq.y, p1);
                p2 = fdot2a(w[2][4 * jj + 1], hq.y, p2);
                p3 = fdot2a(w[3][4 * jj + 1], hq.y, p3);
                p0 = fdot2a(w[0][4 * jj + 2], hq.z, p0);
                p1 = fdot2a(w[1][4 * jj + 2], hq.z, p1);
                p2 = fdot2a(w[2][4 * jj + 2], hq.z, p2);
                p3 = fdot2a(w[3][4 * jj + 2], hq.z, p3);
                p0 = fdot2a(w[0][4 * jj + 3], hq.w, p0);
                p1 = fdot2a(w[1][4 * jj + 3], hq.w, p1);
                p2 = fdot2a(w[2][4 * jj + 3], hq.w, p2);
                p3 = fdot2a(w[3][4 * jj + 3], hq.w, p3);
            }
            // inject x-preact + bias into gate kc only (this thread's G row)
            {
                uint32_t d = ((const uint32_t*)&gblk)[j >> 1];
                uint16_t us = (uint16_t)((j & 1) ? (d >> 16) : (d & 0xffff));
                float gxb = (float)__builtin_bit_cast(f16, us) + bias;
                p0 = __builtin_fmaf(mk0, gxb, p0);
                p1 = __builtin_fmaf(mk1, gxb, p1);
                p2 = __builtin_fmaf(mk2, gxb, p2);
                p3 = __builtin_fmaf(mk3, gxb, p3);
            }
            // DPP quad butterfly all-reduce across the 4 kc lanes
            p0 += qperm<0xB1>(p0); p1 += qperm<0xB1>(p1);
            p2 += qperm<0xB1>(p2); p3 += qperm<0xB1>(p3);
            p0 += qperm<0x4E>(p0); p1 += qperm<0x4E>(p1);
            p2 += qperm<0x4E>(p2); p3 += qperm<0x4E>(p3);
            // elementwise cell update (identical in all 4 kc lanes)
            float si = fsig(p0), sf = fsig(p1), so = fsig(p3);
            c = sf * c + si * ftanh(p2);
            h = so * ftanh(c);
            if (kc == 0) hcur[u] = (f16)h;
            // LDS-only drain + barrier: G prefetch stays in flight across it
            __asm__ __volatile__("s_waitcnt lgkmcnt(0)\n\ts_barrier" ::: "memory");
        }
        gblk = gnblk;
    }
    if ((flags & 1) && t < 16) {                  // flush final step's h
        uint4 hv16 = *(const uint4*)(hb[(2048 - 1) & 1] + t * 8);
        *(uint4*)(toutp + (size_t)(S - 1) * 256) = hv16;
    }
    if ((flags & 2) && kc == 0) hfin[b * 256 + dir * 128 + u] = h;
}

// ---------------- output projection ----------------

__global__ __launch_bounds__(128) void k_out(const float* __restrict__ hp,  // [64][256]
                                             const float* __restrict__ Wo,  // [88][256]
                                             const float* __restrict__ bo,  // [88]
                                             float* __restrict__ out) {     // [64][88]
    const int b = blockIdx.x;
    const int t = threadIdx.x;
    __shared__ float hs[256];
    hs[t] = hp[b * 256 + t];
    hs[t + 128] = hp[b * 256 + 128 + t];
    __syncthreads();
    if (t < 88) {
        float acc = bo[t];
        const float* wr = Wo + t * 256;
#pragma unroll 4
        for (int k = 0; k < 256; ++k) acc += wr[k] * hs[k];
        out[b * 88 + t] = acc;
    }
}

// ---------------- launch ----------------

extern "C" void kernel_launch(void* const* d_in, const int* in_sizes, int n_in,
                              void* d_out, int out_size, void* d_ws, size_t ws_size,
                              hipStream_t stream) {
    const float* x    = (const float*)d_in[0];
    const float* Wtih = (const float*)d_in[1];
    const float* Wthh = (const float*)d_in[2];
    const float* btih = (const float*)d_in[3];
    const float* bthh = (const float*)d_in[4];
    const float* Wpih = (const float*)d_in[5];
    const float* Wphh = (const float*)d_in[6];
    const float* bpih = (const float*)d_in[7];
    const float* bphh = (const float*)d_in[8];
    const float* Wo   = (const float*)d_in[9];
    const float* bo   = (const float*)d_in[10];

    char* ws = (char*)d_ws;
    f16*   xh    = (f16*)(ws + 0);            //  67,108,864 B  [131072][256]
    f16*   G     = (f16*)(ws + 67108864);     // 268,435,456 B  [256][64][1024][8]
    f16*   tout  = (f16*)(ws + 335544320);    //  67,108,864 B  [131072][256]
    f16*   wtih  = (f16*)(ws + 402653184);    //     524,288 B
    f16*   wthh  = (f16*)(ws + 403177472);    //     262,144 B
    f16*   wpih  = (f16*)(ws + 403439616);    //     524,288 B
    f16*   wphh  = (f16*)(ws + 403963904);    //     262,144 B
    float* hp    = (float*)(ws + 404226048);  //      65,536 B  (~405 MB total)

    k_convert_x<<<16384, 256, 0, stream>>>(x, xh);
    k_convert_w<<<128, 256, 0, stream>>>(Wtih, wtih, 32768);
    k_convert_w<<<64,  256, 0, stream>>>(Wthh, wthh, 16384);
    k_convert_w<<<128, 256, 0, stream>>>(Wpih, wpih, 32768);
    k_convert_w<<<64,  256, 0, stream>>>(Wphh, wphh, 16384);

    // G = blocked (xh @ Wt_ih^T)
    k_gemm<<<dim3(1024, 8), 256, 0, stream>>>(xh, wtih, G, 131072, 1024, 256);
    // time-level scan -> tout
    k_lstm<<<128, 512, 0, stream>>>(G, wthh, btih, bthh, tout, nullptr, 2048, 1);
    // G = blocked (tout @ Wp_ih^T)
    k_gemm<<<dim3(1024, 8), 256, 0, stream>>>(tout, wpih, G, 131072, 1024, 256);
    // pitch-level scan -> final h
    k_lstm<<<128, 512, 0, stream>>>(G, wphh, bpih, bphh, nullptr, hp, 2048, 2);
    // output projection
    k_out<<<64, 128, 0, stream>>>(hp, Wo, bo, (float*)d_out);
}

// Round 6
// 2618.121 us; speedup vs baseline: 1.3249x; 1.3101x over previous
//
#include <hip/hip_runtime.h>
#include <hip/hip_fp16.h>
#include <stdint.h>

// MDRNN: 2-level bidirectional LSTM, S=2048 steps, B=64, H=128, I=256, O=88.
// Scan v5: split-K (4 lanes/unit) + DPP quad butterfly, weights resident
// (R5 evidence: VGPR=88 = exact working set). New: cell update de-duplicated
// across the quad (each lane activates ONE gate via unified sig/tanh form,
// then 4 DPP broadcasts) -> trans ops 10->4 per thread-step; bias folded
// into GEMM epilogue; 8-deep accumulator split for ILP.

typedef _Float16 f16;
typedef _Float16 f16x2 __attribute__((ext_vector_type(2)));
typedef _Float16 f16x4 __attribute__((ext_vector_type(4)));
typedef _Float16 f16x8 __attribute__((ext_vector_type(8)));
typedef float f32x4 __attribute__((ext_vector_type(4)));

#if defined(__has_builtin)
#if __has_builtin(__builtin_amdgcn_fdot2)
#define HAVE_FDOT2 1
#endif
#if __has_builtin(__builtin_amdgcn_rcpf)
#define FRCP(x) __builtin_amdgcn_rcpf(x)
#else
#define FRCP(x) (1.f / (x))
#endif
#if __has_builtin(__builtin_amdgcn_exp2f)
#define FEXP2(x) __builtin_amdgcn_exp2f(x)
#else
#define FEXP2(x) __exp2f(x)
#endif
#endif

static __device__ __forceinline__ float fdot2a(uint32_t a, uint32_t b, float c) {
#ifdef HAVE_FDOT2
    return __builtin_amdgcn_fdot2(__builtin_bit_cast(f16x2, a),
                                  __builtin_bit_cast(f16x2, b), c, false);
#else
    f16x2 av = __builtin_bit_cast(f16x2, a), bv = __builtin_bit_cast(f16x2, b);
    return c + (float)av.x * (float)bv.x + (float)av.y * (float)bv.y;
#endif
}

template <int CTRL>
static __device__ __forceinline__ float qperm(float v) {
    int r = __builtin_amdgcn_update_dpp(0, __builtin_bit_cast(int, v), CTRL, 0xf, 0xf, true);
    return __builtin_bit_cast(float, r);
}

// ---------------- conversions ----------------

__global__ __launch_bounds__(256) void k_convert_x(const float* __restrict__ x,
                                                   f16* __restrict__ xh) {
    size_t id = (size_t)blockIdx.x * 256 + threadIdx.x;  // 4,194,304 threads x 8 elems
    const float4* src = (const float4*)(x + id * 8);
    float4 v0 = src[0], v1 = src[1];
    f16x8 o = {(f16)v0.x, (f16)v0.y, (f16)v0.z, (f16)v0.w,
               (f16)v1.x, (f16)v1.y, (f16)v1.z, (f16)v1.w};
    *(f16x8*)(xh + id * 8) = o;
}

__global__ __launch_bounds__(256) void k_convert_w(const float* __restrict__ src,
                                                   f16* __restrict__ dst, int n8) {
    int id = blockIdx.x * 256 + threadIdx.x;
    if (id >= n8) return;
    const float4* sp = (const float4*)(src + (size_t)id * 8);
    float4 v0 = sp[0], v1 = sp[1];
    f16x8 o = {(f16)v0.x, (f16)v0.y, (f16)v0.z, (f16)v0.w,
               (f16)v1.x, (f16)v1.y, (f16)v1.z, (f16)v1.w};
    *(f16x8*)(dst + (size_t)id * 8) = o;
}

// ---------------- MFMA GEMM into block-transposed G, bias fused ----------------
// C layout: [s/8][b][n][s%8]  (M = b*2048+s, n = 0..1023); C[n] += bias0[n]+bias1[n]

#define BM 128
#define BN 128
#define BKK 32
#define LDT 40   // padded LDS row stride (fp16 elems)

__global__ __launch_bounds__(256) void k_gemm(const f16* __restrict__ A,
                                              const f16* __restrict__ B,
                                              f16* __restrict__ C,
                                              const float* __restrict__ bias0,
                                              const float* __restrict__ bias1,
                                              int M, int N, int K) {
    __shared__ __align__(16) f16 As[BM * LDT];
    __shared__ __align__(16) f16 Bs[BN * LDT];
    const int tid  = threadIdx.x;
    const int m0   = blockIdx.x * BM;
    const int n0   = blockIdx.y * BN;
    const int lane = tid & 63;
    const int wave = tid >> 6;
    const int wm   = (wave & 1) * 64;
    const int wn   = (wave >> 1) * 64;
    const int r    = tid >> 1;
    const int koff = (tid & 1) * 16;
    const int mrow = lane & 15;
    const int kof  = (lane >> 4) * 8;

    // per-thread bias for the 4 output columns (off critical path)
    float bb[4];
#pragma unroll
    for (int j = 0; j < 4; ++j) {
        int cn = n0 + wn + j * 16 + (lane & 15);
        bb[j] = bias0[cn] + bias1[cn];
    }

    f32x4 acc[4][4];
#pragma unroll
    for (int i = 0; i < 4; ++i)
#pragma unroll
        for (int j = 0; j < 4; ++j) acc[i][j] = (f32x4){0.f, 0.f, 0.f, 0.f};

    for (int k0 = 0; k0 < K; k0 += BKK) {
        uint4 a0 = *(const uint4*)(A + (size_t)(m0 + r) * K + k0 + koff);
        uint4 a1 = *(const uint4*)(A + (size_t)(m0 + r) * K + k0 + koff + 8);
        uint4 b0 = *(const uint4*)(B + (size_t)(n0 + r) * K + k0 + koff);
        uint4 b1 = *(const uint4*)(B + (size_t)(n0 + r) * K + k0 + koff + 8);
        *(uint4*)(As + r * LDT + koff)     = a0;
        *(uint4*)(As + r * LDT + koff + 8) = a1;
        *(uint4*)(Bs + r * LDT + koff)     = b0;
        *(uint4*)(Bs + r * LDT + koff + 8) = b1;
        __syncthreads();
        f16x8 af[4], bfr[4];
#pragma unroll
        for (int i = 0; i < 4; ++i)
            af[i] = *(const f16x8*)(As + (wm + i * 16 + mrow) * LDT + kof);
#pragma unroll
        for (int j = 0; j < 4; ++j)
            bfr[j] = *(const f16x8*)(Bs + (wn + j * 16 + mrow) * LDT + kof);
#pragma unroll
        for (int i = 0; i < 4; ++i)
#pragma unroll
            for (int j = 0; j < 4; ++j)
                acc[i][j] = __builtin_amdgcn_mfma_f32_16x16x32_f16(af[i], bfr[j], acc[i][j], 0, 0, 0);
        __syncthreads();
    }
    const int crow = (lane >> 4) * 4;
#pragma unroll
    for (int i = 0; i < 4; ++i) {
#pragma unroll
        for (int j = 0; j < 4; ++j) {
            int cn = n0 + wn + j * 16 + (lane & 15);
            int m  = m0 + wm + i * 16 + crow;
            int bbk = m >> 11;         // batch
            int s   = m & 2047;        // step
            f16x4 v = {(f16)(acc[i][j][0] + bb[j]), (f16)(acc[i][j][1] + bb[j]),
                       (f16)(acc[i][j][2] + bb[j]), (f16)(acc[i][j][3] + bb[j])};
            size_t addr = ((((size_t)(s >> 3) * 64 + bbk) * 1024) + cn) * 8 + (s & 7);
            *(f16x4*)(C + addr) = v;
        }
    }
}

// ---------------- recurrent LSTM scan ----------------
// One WG per (batch, direction), 512 threads: t = u*4 + kc
// Per step: 64 fdot2 into 8 accumulators -> combine -> masked x-preact inject
// -> quad butterfly all-reduce (4 gates) -> each lane keeps ITS gate, applies
// unified activation (1 exp + 1 rcp) -> 4 quad-broadcasts -> cell update with
// one shared tanh(c) (1 exp + 1 rcp). Trans ops: 4/thread/step (was 10).

__global__ void __attribute__((amdgpu_flat_work_group_size(512, 512),
                               amdgpu_waves_per_eu(2, 2))) k_lstm(
    const f16* __restrict__ G,              // [S/8][64][1024][8], bias pre-added
    const f16* __restrict__ Whh,            // [2][512][128] fp16
    f16* __restrict__ tout,                 // [131072][256] fp16 (flags&1)
    float* __restrict__ hfin,               // [64][256] fp32 (flags&2)
    const int S, const int flags) {
    const int b   = blockIdx.x >> 1;
    const int dir = blockIdx.x & 1;
    const int t   = threadIdx.x;
    const int u   = t >> 2;
    const int kc  = t & 3;

    __shared__ __align__(16) f16 hb[2][128];

    uint32_t w[4][16];
#pragma unroll
    for (int q = 0; q < 4; ++q) {
        const uint4* wp = (const uint4*)(Whh + ((size_t)(dir * 512 + q * 128 + u) * 128 + kc * 32));
#pragma unroll
        for (int jj = 0; jj < 4; ++jj) {
            uint4 qd = wp[jj];
            w[q][4 * jj + 0] = qd.x; w[q][4 * jj + 1] = qd.y;
            w[q][4 * jj + 2] = qd.z; w[q][4 * jj + 3] = qd.w;
        }
    }
#pragma unroll
    for (int q = 0; q < 4; ++q)
#pragma unroll
        for (int i = 0; i < 16; ++i) __asm__("" : "+v"(w[q][i]));

    const int rowg = dir * 512 + kc * 128 + u;    // this thread's G row
    // unified activation constants: act = 1 - B * rcp(1 + exp2(k*x))
    // sigmoid: B=1, k=log2(e); tanh (gate 2): B=2, k=2*log2(e)
    const float kact = (kc == 2) ? 2.8853900818f : 1.4426950409f;
    const float Bact = (kc == 2) ? 2.0f : 1.0f;
    const float mk0 = (kc == 0) ? 1.f : 0.f;
    const float mk1 = (kc == 1) ? 1.f : 0.f;
    const float mk2 = (kc == 2) ? 1.f : 0.f;
    const float mk3 = (kc == 3) ? 1.f : 0.f;

    if (t < 64) ((uint32_t*)hb)[64 + t] = 0u;     // zero hb[1] (h(-1))
    float c = 0.f, h = 0.f;
    __syncthreads();

    const f16* gp = G + ((size_t)b * 1024 + rowg) * 8;
    f16* toutp = tout + ((size_t)b * 2048) * 256 + dir * 128 + (t & 15) * 8;

    uint4 gblk = *(const uint4*)(gp);             // steps 0..7
    for (int sb = 0; sb < S; sb += 8) {
        const size_t nblk = (size_t)((sb + 8 < S) ? (sb >> 3) + 1 : (sb >> 3));
        uint4 gnblk = *(const uint4*)(gp + nblk * 524288);  // prefetch next block
#pragma unroll
        for (int j = 0; j < 8; ++j) {
            const int s = sb + j;
            f16* hcur = hb[j & 1];
            const f16* hprv = hb[(j & 1) ^ 1];
            if ((flags & 1) && t < 16 && s > 0) {
                uint4 hv16 = *(const uint4*)(hprv + t * 8);
                *(uint4*)(toutp + (size_t)(s - 1) * 256) = hv16;
            }
            // 8 accumulators (2 per gate) for ILP
            float p0a = 0.f, p1a = 0.f, p2a = 0.f, p3a = 0.f;
            float p0b = 0.f, p1b = 0.f, p2b = 0.f, p3b = 0.f;
            const uint4* hv = (const uint4*)(hprv + kc * 32);
#pragma unroll
            for (int jj = 0; jj < 4; ++jj) {
                uint4 hq = hv[jj];
                p0a = fdot2a(w[0][4 * jj + 0], hq.x, p0a);
                p1a = fdot2a(w[1][4 * jj + 0], hq.x, p1a);
                p2a = fdot2a(w[2][4 * jj + 0], hq.x, p2a);
                p3a = fdot2a(w[3][4 * jj + 0], hq.x, p3a);
                p0b = fdot2a(w[0][4 * jj + 1], hq.y, p0b);
                p1b = fdot2a(w[1][4 * jj + 1], hq.y, p1b);
                p2b = fdot2a(w[2][4 * jj + 1], hq.y, p2b);
                p3b = fdot2a(w[3][4 * jj + 1], hq.y, p3b);
                p0a = fdot2a(w[0][4 * jj + 2], hq.z, p0a);
                p1a = fdot2a(w[1][4 * jj + 2], hq.z, p1a);
                p2a = fdot2a(w[2][4 * jj + 2], hq.z, p2a);
                p3a = fdot2a(w[3][4 * jj + 2], hq.z, p3a);
                p0b = fdot2a(w[0][4 * jj + 3], hq.w, p0b);
                p1b = fdot2a(w[1][4 * jj + 3], hq.w, p1b);
                p2b = fdot2a(w[2][4 * jj + 3], hq.w, p2b);
                p3b = fdot2a(w[3][4 * jj + 3], hq.w, p3b);
            }
            float p0 = p0a + p0b, p1 = p1a + p1b, p2 = p2a + p2b, p3 = p3a + p3b;
            // inject x-preact (bias pre-added in GEMM) into gate kc only
            {
                uint32_t d = ((const uint32_t*)&gblk)[j >> 1];
                uint16_t us = (uint16_t)((j & 1) ? (d >> 16) : (d & 0xffff));
                float gxb = (float)__builtin_bit_cast(f16, us);
                p0 = __builtin_fmaf(mk0, gxb, p0);
                p1 = __builtin_fmaf(mk1, gxb, p1);
                p2 = __builtin_fmaf(mk2, gxb, p2);
                p3 = __builtin_fmaf(mk3, gxb, p3);
            }
            // DPP quad butterfly all-reduce across the 4 kc lanes
            p0 += qperm<0xB1>(p0); p1 += qperm<0xB1>(p1);
            p2 += qperm<0xB1>(p2); p3 += qperm<0xB1>(p3);
            p0 += qperm<0x4E>(p0); p1 += qperm<0x4E>(p1);
            p2 += qperm<0x4E>(p2); p3 += qperm<0x4E>(p3);
            // each lane keeps only ITS gate and activates it (1 exp + 1 rcp)
            float v = (kc == 0) ? p0 : (kc == 1) ? p1 : (kc == 2) ? p2 : p3;
            float act = __builtin_fmaf(-Bact, FRCP(1.f + FEXP2(v * kact)), 1.f);
            // quad-broadcast the 4 activated gates
            float gi = qperm<0x00>(act);
            float gf = qperm<0x55>(act);
            float gg = qperm<0xAA>(act);
            float go = qperm<0xFF>(act);
            // cell update (replicated, identical across the quad)
            c = __builtin_fmaf(gf, c, gi * gg);
            float tc = __builtin_fmaf(-2.f, FRCP(1.f + FEXP2(c * 2.8853900818f)), 1.f);
            h = go * tc;
            if (kc == 0) hcur[u] = (f16)h;
            // LDS-only drain + barrier: G prefetch stays in flight across it
            __asm__ __volatile__("s_waitcnt lgkmcnt(0)\n\ts_barrier" ::: "memory");
        }
        gblk = gnblk;
    }
    if ((flags & 1) && t < 16) {                  // flush final step's h
        uint4 hv16 = *(const uint4*)(hb[(2048 - 1) & 1] + t * 8);
        *(uint4*)(toutp + (size_t)(S - 1) * 256) = hv16;
    }
    if ((flags & 2) && kc == 0) hfin[b * 256 + dir * 128 + u] = h;
}

// ---------------- output projection ----------------

__global__ __launch_bounds__(128) void k_out(const float* __restrict__ hp,  // [64][256]
                                             const float* __restrict__ Wo,  // [88][256]
                                             const float* __restrict__ bo,  // [88]
                                             float* __restrict__ out) {     // [64][88]
    const int b = blockIdx.x;
    const int t = threadIdx.x;
    __shared__ float hs[256];
    hs[t] = hp[b * 256 + t];
    hs[t + 128] = hp[b * 256 + 128 + t];
    __syncthreads();
    if (t < 88) {
        float acc = bo[t];
        const float* wr = Wo + t * 256;
#pragma unroll 4
        for (int k = 0; k < 256; ++k) acc += wr[k] * hs[k];
        out[b * 88 + t] = acc;
    }
}

// ---------------- launch ----------------

extern "C" void kernel_launch(void* const* d_in, const int* in_sizes, int n_in,
                              void* d_out, int out_size, void* d_ws, size_t ws_size,
                              hipStream_t stream) {
    const float* x    = (const float*)d_in[0];
    const float* Wtih = (const float*)d_in[1];
    const float* Wthh = (const float*)d_in[2];
    const float* btih = (const float*)d_in[3];
    const float* bthh = (const float*)d_in[4];
    const float* Wpih = (const float*)d_in[5];
    const float* Wphh = (const float*)d_in[6];
    const float* bpih = (const float*)d_in[7];
    const float* bphh = (const float*)d_in[8];
    const float* Wo   = (const float*)d_in[9];
    const float* bo   = (const float*)d_in[10];

    char* ws = (char*)d_ws;
    f16*   xh    = (f16*)(ws + 0);            //  67,108,864 B  [131072][256]
    f16*   G     = (f16*)(ws + 67108864);     // 268,435,456 B  [256][64][1024][8]
    f16*   tout  = (f16*)(ws + 335544320);    //  67,108,864 B  [131072][256]
    f16*   wtih  = (f16*)(ws + 402653184);    //     524,288 B
    f16*   wthh  = (f16*)(ws + 403177472);    //     262,144 B
    f16*   wpih  = (f16*)(ws + 403439616);    //     524,288 B
    f16*   wphh  = (f16*)(ws + 403963904);    //     262,144 B
    float* hp    = (float*)(ws + 404226048);  //      65,536 B  (~405 MB total)

    k_convert_x<<<16384, 256, 0, stream>>>(x, xh);
    k_convert_w<<<128, 256, 0, stream>>>(Wtih, wtih, 32768);
    k_convert_w<<<64,  256, 0, stream>>>(Wthh, wthh, 16384);
    k_convert_w<<<128, 256, 0, stream>>>(Wpih, wpih, 32768);
    k_convert_w<<<64,  256, 0, stream>>>(Wphh, wphh, 16384);

    // G = blocked (xh @ Wt_ih^T) + bt_ih + bt_hh
    k_gemm<<<dim3(1024, 8), 256, 0, stream>>>(xh, wtih, G, btih, bthh, 131072, 1024, 256);
    // time-level scan -> tout
    k_lstm<<<128, 512, 0, stream>>>(G, wthh, tout, nullptr, 2048, 1);
    // G = blocked (tout @ Wp_ih^T) + bp_ih + bp_hh
    k_gemm<<<dim3(1024, 8), 256, 0, stream>>>(tout, wpih, G, bpih, bphh, 131072, 1024, 256);
    // pitch-level scan -> final h
    k_lstm<<<128, 512, 0, stream>>>(G, wphh, nullptr, hp, 2048, 2);
    // output projection
    k_out<<<64, 128, 0, stream>>>(hp, Wo, bo, (float*)d_out);
}